// Round 7
// baseline (461.032 us; speedup 1.0000x reference)
//
#include <hip/hip_runtime.h>
#include <stdint.h>

#define ALPHA 1.0f

typedef int i32x4 __attribute__((ext_vector_type(4)));

typedef __attribute__((address_space(3))) void lds_void_t;
typedef const __attribute__((address_space(1))) void global_void_t;

__device__ __forceinline__ void async16(const void* g, void* l) {
    __builtin_amdgcn_global_load_lds((global_void_t*)g, (lds_void_t*)l, 16, 0, 0);
}

__device__ __forceinline__ signed char q8(float v, float inv) {
    float f = fminf(fmaxf(v * inv, -127.f), 127.f);
    return (signed char)__float2int_rn(f);
}

// ---------------------------------------------------------------------------
// Kernel 1 (merged): blocks [0,M) quantize X token-rows to int8 with per-row
// scale sx; blocks [M, M+ceil(nnz/256)) boundary-detect sorted `rows` into
// rstart/rend.  Rows absent from `rows` leave rstart[r]==rend[r] (poison).
// ---------------------------------------------------------------------------
__global__ __launch_bounds__(256) void prep_kernel(
    const float* __restrict__ x, const int* __restrict__ rows,
    int* __restrict__ rstart, int* __restrict__ rend,
    signed char* __restrict__ X8, float* __restrict__ sx, int M, int nnz) {
    const int b = blockIdx.x;
    if (b < M) {
        __shared__ float red[4];
        const int t = threadIdx.x;
        const float4* xr = (const float4*)(x + (size_t)b * 4096);
        float4 v[4];
        float mx = 0.f;
#pragma unroll
        for (int i = 0; i < 4; i++) {
            v[i] = xr[t * 4 + i];
            mx = fmaxf(mx, fmaxf(fmaxf(fabsf(v[i].x), fabsf(v[i].y)),
                                 fmaxf(fabsf(v[i].z), fabsf(v[i].w))));
        }
#pragma unroll
        for (int o = 32; o > 0; o >>= 1) mx = fmaxf(mx, __shfl_xor(mx, o));
        if ((t & 63) == 0) red[t >> 6] = mx;
        __syncthreads();
        mx = fmaxf(fmaxf(red[0], red[1]), fmaxf(red[2], red[3]));
        mx = fmaxf(mx, 1e-20f);
        if (t == 0) sx[b] = mx / 127.f;
        const float inv = 127.f / mx;
        union { signed char c[16]; int4 w; } u;
#pragma unroll
        for (int i = 0; i < 4; i++) {
            u.c[i * 4 + 0] = q8(v[i].x, inv);
            u.c[i * 4 + 1] = q8(v[i].y, inv);
            u.c[i * 4 + 2] = q8(v[i].z, inv);
            u.c[i * 4 + 3] = q8(v[i].w, inv);
        }
        ((int4*)(X8 + (size_t)b * 4096))[t] = u.w;
    } else {
        int i = (b - M) * 256 + threadIdx.x;
        if (i < nnz) {
            int r = rows[i];
            if (i == 0 || rows[i - 1] != r) rstart[r] = i;
            if (i == nnz - 1 || rows[i + 1] != r) rend[r] = i + 1;
        }
    }
}

// ---------------------------------------------------------------------------
// Kernel 2 v2: build int8 W, one output row per block.  (unchanged)
//   Dense dequant in registers; LDS only for the sparse scatter (swizzled).
// ---------------------------------------------------------------------------
__global__ __launch_bounds__(256) void build_w8_kernel(
    const int* __restrict__ packed, const float* __restrict__ scales,
    const float* __restrict__ vals, const int* __restrict__ cols,
    const int* __restrict__ rstart, const int* __restrict__ rend,
    signed char* __restrict__ W8, float* __restrict__ sw) {
    __shared__ __align__(16) float acc[4096];   // sparse-only, swizzled
    __shared__ float red[4];
    const int r = blockIdx.x;
    const int t = threadIdx.x;
    const float s = scales[r];

    const int4* prow4 = (const int4*)(packed + (size_t)r * 2048);
    int4 p0 = prow4[2 * t], p1 = prow4[2 * t + 1];

    const int lo = rstart[r], hi = rend[r];   // equal (poison) if row empty

    float4 sp[4] = {float4{0,0,0,0}, float4{0,0,0,0},
                    float4{0,0,0,0}, float4{0,0,0,0}};
    if (hi > lo) {                             // block-uniform branch
        char* ab = (char*)acc;
#pragma unroll
        for (int i = 0; i < 4; i++) {
            int b = 64 * t + 16 * i;
            *(float4*)(ab + (b ^ (((b >> 7) & 7) << 4))) = float4{0, 0, 0, 0};
        }
        __syncthreads();
        for (int i = lo + t; i < hi; i += 256) {
            int b = cols[i] * 4;
            atomicAdd((float*)(ab + (b ^ (((b >> 7) & 7) << 4))),
                      vals[i] * ALPHA);
        }
        __syncthreads();
#pragma unroll
        for (int i = 0; i < 4; i++) {
            int b = 64 * t + 16 * i;
            sp[i] = *(const float4*)(ab + (b ^ (((b >> 7) & 7) << 4)));
        }
    }

    float w[16];
    {
        int pv[8] = {p0.x, p0.y, p0.z, p0.w, p1.x, p1.y, p1.z, p1.w};
#pragma unroll
        for (int q = 0; q < 8; q++) {
            w[2 * q]     = (float)((pv[q] & 0xF) - 8) * s;
            w[2 * q + 1] = (float)(((pv[q] >> 4) & 0xF) - 8) * s;
        }
    }
    const float* spf = (const float*)sp;
    float mx = 0.f;
#pragma unroll
    for (int k = 0; k < 16; k++) {
        w[k] += spf[k];
        mx = fmaxf(mx, fabsf(w[k]));
    }
#pragma unroll
    for (int o = 32; o > 0; o >>= 1) mx = fmaxf(mx, __shfl_xor(mx, o));
    if ((t & 63) == 0) red[t >> 6] = mx;
    __syncthreads();
    mx = fmaxf(fmaxf(red[0], red[1]), fmaxf(red[2], red[3]));
    mx = fmaxf(mx, 1e-20f);
    if (t == 0) sw[r] = mx / 127.f;
    const float inv = 127.f / mx;

    union { signed char c[16]; int4 v; } u;
#pragma unroll
    for (int k = 0; k < 16; k++) u.c[k] = q8(w[k], inv);
    ((int4*)(W8 + (size_t)r * 4096))[t] = u.v;
}

// ---------------------------------------------------------------------------
// Kernel 3: int8 NT GEMM, A-from-L2, spill-free (round-6 fix).
//   BM=128, BN=256, BK=128 bytes, 512 thr = 8 waves (2M x 4N), 64x64/wave.
//   A (X8, 8.4 MB, L2/L3-resident) read directly into registers for the
//   CURRENT tile only (no cross-iter ping-pong: that was +64 VGPR -> spills
//   -> spill VMEM corrupts counted vmcnt -> round-6 race).  Live set
//   acc(64) + <=6 A frags(24) + B frags(32 overlapped) ~= 120 <= 128 cap.
//   A loads issue 1-3 phases ahead of use; ALL A loads in a phase precede
//   the STAGEs so compiler auto-waits (counted from issue order) never
//   force young B-stages to drain.  B: triple-buffered LDS, distance 2,
//   p3 counted vmcnt = 8 A + 4*pref stages issued this iter.  B swizzle,
//   phase skeleton, epilogue identical to proven round-3 kernel.
// ---------------------------------------------------------------------------
__global__ __launch_bounds__(512) void gemm_kernel(
    const signed char* __restrict__ Xq,   // [M,K] i8
    const signed char* __restrict__ Wq,   // [N,K] i8
    const float* __restrict__ sx,         // [M]
    const float* __restrict__ sw,         // [N]
    float* __restrict__ C,                // [M,N] fp32
    int M, int N, int K) {
    __shared__ __align__(16) signed char smem[3 * 32768];   // B only

    const int tid  = threadIdx.x;
    const int wid  = tid >> 6;
    const int lane = tid & 63;
    const int wr = wid >> 2;        // 0..1 (M)
    const int wc = wid & 3;         // 0..3 (N)

    // bijective XCD-chunked block swizzle (nwg = 688, %8 == 0).
    // nt varies fastest within an XCD chunk -> concurrent blocks on an XCD
    // share the same A panel (512 KB, L2-resident) and stream B.
    const int nwg = gridDim.x;
    const int bid = blockIdx.x;
    const int qc = nwg >> 3, rr = nwg & 7;
    const int xcd = bid & 7, loc = bid >> 3;
    const int swz = (xcd < rr ? xcd * (qc + 1) : rr * (qc + 1) + (xcd - rr) * qc) + loc;
    const int tn = N >> 8;
    const int nt = swz % tn;
    const int mt = swz / tn;
    const int m0 = mt << 7;
    const int n0 = nt << 8;

    // B staging: gload_lds dest linear, global SOURCE pre-swizzled (rule 21)
    const int sr = tid >> 3;                         // row (load0); load1 = +64
    const int sc = ((tid & 7) ^ (sr & 7)) << 4;      // swizzled src byte col
    const int lw0 = wid << 10;
    const int lw1 = 8192 + (wid << 10);

    const signed char* Bw0 = Wq + (size_t)n0 * K;
    const signed char* Bw1 = Wq + (size_t)(n0 + 128) * K;

#define STAGE(gbase, ldsbase) do {                                         \
        async16((gbase) + (size_t)sr * K + sc, (ldsbase) + lw0);           \
        async16((gbase) + (size_t)(sr + 64) * K + sc, (ldsbase) + lw1);    \
    } while (0)

    // fragment read constants
    const int fm = lane & 15;
    const int fk16 = (lane >> 4) << 4;                   // A k-byte offset
    const int slot0 = ((lane >> 4) ^ (lane & 7)) << 4;   // B LDS k-slot, ks0
    const int slot1 = slot0 ^ 64;                        // ks1
    const int arow_base = wr * 64;
    const int brow_base = wc * 64;

    // per-thread A row base (row = m0 + arow_base + mi*16 + fm)
    const signed char* Arow =
        Xq + (size_t)(m0 + arow_base + fm) * K + fk16;

    // A direct from global: delivers exactly what the swizzled-LDS path did
    // (G chunk = (lane>>4) for ks0, +4 for ks1; verified lane algebra)
#define LDAG(mi, ks, kb) \
    (*(const i32x4*)(Arow + (size_t)(mi) * 16 * K + (kb) + (ks) * 64))
#define LDB(buf, nj, sl) \
    (*(const i32x4*)((buf) + (size_t)(brow_base + (nj) * 16 + fm) * 128 + (sl)))

#define MFMA8(m0i, m1i, aX, aY, B0, B1, B2, B3) do {                        \
        __builtin_amdgcn_s_setprio(1);                                      \
        acc[m0i][0] = __builtin_amdgcn_mfma_i32_16x16x64_i8(aX, B0, acc[m0i][0], 0, 0, 0); \
        acc[m1i][0] = __builtin_amdgcn_mfma_i32_16x16x64_i8(aY, B0, acc[m1i][0], 0, 0, 0); \
        acc[m0i][1] = __builtin_amdgcn_mfma_i32_16x16x64_i8(aX, B1, acc[m0i][1], 0, 0, 0); \
        acc[m1i][1] = __builtin_amdgcn_mfma_i32_16x16x64_i8(aY, B1, acc[m1i][1], 0, 0, 0); \
        acc[m0i][2] = __builtin_amdgcn_mfma_i32_16x16x64_i8(aX, B2, acc[m0i][2], 0, 0, 0); \
        acc[m1i][2] = __builtin_amdgcn_mfma_i32_16x16x64_i8(aY, B2, acc[m1i][2], 0, 0, 0); \
        acc[m0i][3] = __builtin_amdgcn_mfma_i32_16x16x64_i8(aX, B3, acc[m0i][3], 0, 0, 0); \
        acc[m1i][3] = __builtin_amdgcn_mfma_i32_16x16x64_i8(aY, B3, acc[m1i][3], 0, 0, 0); \
        __builtin_amdgcn_s_setprio(0);                                      \
    } while (0)

    i32x4 acc[4][4];
#pragma unroll
    for (int i = 0; i < 4; i++)
#pragma unroll
        for (int j = 0; j < 4; j++) acc[i][j] = (i32x4){0, 0, 0, 0};

    const int NT = K >> 7;   // 128-byte K-tiles (32)

    // prologue: stage B of T0 -> buf0 (4 async16), T1 -> buf1 (4),
    // wait T0's 4 (oldest 4 of 8), barrier.
    STAGE(Bw0,       smem);
    STAGE(Bw1,       smem + 16384);
    STAGE(Bw0 + 128, smem + 32768);
    STAGE(Bw1 + 128, smem + 32768 + 16384);
    asm volatile("s_waitcnt vmcnt(4)" ::: "memory");
    __builtin_amdgcn_s_barrier();
    __builtin_amdgcn_sched_barrier(0);

    int cur = 0;
    for (int it = 0; it < NT; ++it) {
        signed char* Bb = smem + cur * 32768;
        int pb = cur + 2; if (pb >= 3) pb -= 3;
        signed char* PB = smem + pb * 32768;
        const bool pref = (it + 2 < NT);
        const int kc = (it + 2) << 7;   // B stage k
        const int k0 = it << 7;         // A load k (current tile)

        // p0: issue 6 A loads (this tile) BEFORE anything else; read B ks0;
        // MFMA rows 0-1 x ks0.  a0/a1 exposure ~150cy; na/ma covered.
        i32x4 a0  = LDAG(0, 0, k0), a1  = LDAG(1, 0, k0);
        i32x4 na0 = LDAG(2, 0, k0), na1 = LDAG(3, 0, k0);
        i32x4 ma0 = LDAG(0, 1, k0), ma1 = LDAG(1, 1, k0);
        i32x4 bA0 = LDB(Bb, 0, slot0), bA1 = LDB(Bb, 1, slot0),
              bA2 = LDB(Bb, 2, slot0), bA3 = LDB(Bb, 3, slot0);
        MFMA8(0, 1, a0, a1, bA0, bA1, bA2, bA3);

        // p1: issue pa loads (used p3) BEFORE the stage; read B ks1;
        // stage B(it+2) low half; MFMA rows 2-3 x ks0
        i32x4 pa2 = LDAG(2, 1, k0), pa3 = LDAG(3, 1, k0);
        i32x4 bB0 = LDB(Bb, 0, slot1), bB1 = LDB(Bb, 1, slot1),
              bB2 = LDB(Bb, 2, slot1), bB3 = LDB(Bb, 3, slot1);
        if (pref) STAGE(Bw0 + kc, PB);
        MFMA8(2, 3, na0, na1, bA0, bA1, bA2, bA3);

        // p2: stage B(it+2) high half; MFMA rows 0-1 x ks1
        if (pref) STAGE(Bw1 + kc, PB + 16384);
        MFMA8(0, 1, ma0, ma1, bB0, bB1, bB2, bB3);

        // p3: counted vmcnt (B(it+1) fully landed: everything issued this
        // iter = 8 A + 4*pref stages is newer), MFMA rows 2-3 x ks1,
        // single end-of-iter barrier.
        if (it + 2 < NT)      { asm volatile("s_waitcnt vmcnt(12)" ::: "memory"); }
        else if (it + 1 < NT) { asm volatile("s_waitcnt vmcnt(8)"  ::: "memory"); }
        MFMA8(2, 3, pa2, pa3, bB0, bB1, bB2, bB3);

        __builtin_amdgcn_s_barrier();
        __builtin_amdgcn_sched_barrier(0);
        cur += 1; if (cur == 3) cur = 0;
    }
#undef STAGE
#undef LDAG
#undef LDB
#undef MFMA8

    // epilogue: C/D layout col = lane&15, row = (lane>>4)*4 + reg
    const int cr = (lane >> 4) << 2;
    const int cc = lane & 15;
#pragma unroll
    for (int mi = 0; mi < 4; ++mi) {
        const int row0 = m0 + wr * 64 + mi * 16 + cr;
        float sxv[4];
#pragma unroll
        for (int r = 0; r < 4; ++r) sxv[r] = sx[row0 + r];
#pragma unroll
        for (int nj = 0; nj < 4; ++nj) {
            const int col = n0 + wc * 64 + nj * 16 + cc;
            const float swc = sw[col];
            float* cp = C + (size_t)row0 * N + col;
#pragma unroll
            for (int r = 0; r < 4; ++r)
                cp[(size_t)r * N] = (float)acc[mi][nj][r] * sxv[r] * swc;
        }
    }
}

extern "C" void kernel_launch(void* const* d_in, const int* in_sizes, int n_in,
                              void* d_out, int out_size, void* d_ws, size_t ws_size,
                              hipStream_t stream) {
    const float* x      = (const float*)d_in[0];
    const float* scales = (const float*)d_in[1];
    const float* vals   = (const float*)d_in[2];
    const int* packed   = (const int*)d_in[3];
    const int* rows     = (const int*)d_in[4];
    const int* cols     = (const int*)d_in[5];
    float* out          = (float*)d_out;

    const int OUT  = in_sizes[1];            // 11008
    const int HALF = in_sizes[3] / OUT;      // 2048
    const int IN   = HALF * 2;               // 4096
    const int M    = in_sizes[0] / IN;       // 2048 tokens
    const int NNZ  = in_sizes[2];            // 2250000

    // workspace: i8 W [OUT,IN] | i8 X [M,IN] | sx[M] | sw[OUT] | rstart | rend
    signed char* W8 = (signed char*)d_ws;
    signed char* X8 = W8 + (size_t)OUT * IN;
    float* sx   = (float*)(X8 + (size_t)M * IN);
    float* sw   = sx + M;
    int* rstart = (int*)(sw + OUT);
    int* rend   = rstart + OUT;

    const int boundsBlocks = (NNZ + 255) / 256;
    prep_kernel<<<M + boundsBlocks, 256, 0, stream>>>(x, rows, rstart, rend,
                                                      X8, sx, M, NNZ);
    build_w8_kernel<<<OUT, 256, 0, stream>>>(packed, scales, vals, cols,
                                             rstart, rend, W8, sw);
    const int nwg = (M / 128) * (OUT / 256);   // 16 * 43 = 688, %8 == 0
    gemm_kernel<<<nwg, 512, 0, stream>>>(X8, W8, sx, sw, out, M, OUT, IN);
}

// Round 8
// 313.194 us; speedup vs baseline: 1.4720x; 1.4720x over previous
//
#include <hip/hip_runtime.h>
#include <stdint.h>

#define ALPHA 1.0f

typedef int i32x4 __attribute__((ext_vector_type(4)));

typedef __attribute__((address_space(3))) void lds_void_t;
typedef const __attribute__((address_space(1))) void global_void_t;

__device__ __forceinline__ void async16(const void* g, void* l) {
    __builtin_amdgcn_global_load_lds((global_void_t*)g, (lds_void_t*)l, 16, 0, 0);
}

__device__ __forceinline__ signed char q8(float v, float inv) {
    float f = fminf(fmaxf(v * inv, -127.f), 127.f);
    return (signed char)__float2int_rn(f);
}

// ---------------------------------------------------------------------------
// Kernel 1 (merged): blocks [0,M) quantize X token-rows to int8 with per-row
// scale sx; blocks [M, M+ceil(nnz/256)) boundary-detect sorted `rows` into
// rstart/rend.  Rows absent from `rows` leave rstart[r]==rend[r] (poison).
// ---------------------------------------------------------------------------
__global__ __launch_bounds__(256) void prep_kernel(
    const float* __restrict__ x, const int* __restrict__ rows,
    int* __restrict__ rstart, int* __restrict__ rend,
    signed char* __restrict__ X8, float* __restrict__ sx, int M, int nnz) {
    const int b = blockIdx.x;
    if (b < M) {
        __shared__ float red[4];
        const int t = threadIdx.x;
        const float4* xr = (const float4*)(x + (size_t)b * 4096);
        float4 v[4];
        float mx = 0.f;
#pragma unroll
        for (int i = 0; i < 4; i++) {
            v[i] = xr[t * 4 + i];
            mx = fmaxf(mx, fmaxf(fmaxf(fabsf(v[i].x), fabsf(v[i].y)),
                                 fmaxf(fabsf(v[i].z), fabsf(v[i].w))));
        }
#pragma unroll
        for (int o = 32; o > 0; o >>= 1) mx = fmaxf(mx, __shfl_xor(mx, o));
        if ((t & 63) == 0) red[t >> 6] = mx;
        __syncthreads();
        mx = fmaxf(fmaxf(red[0], red[1]), fmaxf(red[2], red[3]));
        mx = fmaxf(mx, 1e-20f);
        if (t == 0) sx[b] = mx / 127.f;
        const float inv = 127.f / mx;
        union { signed char c[16]; int4 w; } u;
#pragma unroll
        for (int i = 0; i < 4; i++) {
            u.c[i * 4 + 0] = q8(v[i].x, inv);
            u.c[i * 4 + 1] = q8(v[i].y, inv);
            u.c[i * 4 + 2] = q8(v[i].z, inv);
            u.c[i * 4 + 3] = q8(v[i].w, inv);
        }
        ((int4*)(X8 + (size_t)b * 4096))[t] = u.w;
    } else {
        int i = (b - M) * 256 + threadIdx.x;
        if (i < nnz) {
            int r = rows[i];
            if (i == 0 || rows[i - 1] != r) rstart[r] = i;
            if (i == nnz - 1 || rows[i + 1] != r) rend[r] = i + 1;
        }
    }
}

// ---------------------------------------------------------------------------
// Kernel 2 v2: build int8 W, one output row per block.
//   Dense dequant in registers; LDS only for the sparse scatter (swizzled).
// ---------------------------------------------------------------------------
__global__ __launch_bounds__(256) void build_w8_kernel(
    const int* __restrict__ packed, const float* __restrict__ scales,
    const float* __restrict__ vals, const int* __restrict__ cols,
    const int* __restrict__ rstart, const int* __restrict__ rend,
    signed char* __restrict__ W8, float* __restrict__ sw) {
    __shared__ __align__(16) float acc[4096];   // sparse-only, swizzled
    __shared__ float red[4];
    const int r = blockIdx.x;
    const int t = threadIdx.x;
    const float s = scales[r];

    const int4* prow4 = (const int4*)(packed + (size_t)r * 2048);
    int4 p0 = prow4[2 * t], p1 = prow4[2 * t + 1];

    const int lo = rstart[r], hi = rend[r];   // equal (poison) if row empty

    float4 sp[4] = {float4{0,0,0,0}, float4{0,0,0,0},
                    float4{0,0,0,0}, float4{0,0,0,0}};
    if (hi > lo) {                             // block-uniform branch
        char* ab = (char*)acc;
#pragma unroll
        for (int i = 0; i < 4; i++) {
            int b = 64 * t + 16 * i;
            *(float4*)(ab + (b ^ (((b >> 7) & 7) << 4))) = float4{0, 0, 0, 0};
        }
        __syncthreads();
        for (int i = lo + t; i < hi; i += 256) {
            int b = cols[i] * 4;
            atomicAdd((float*)(ab + (b ^ (((b >> 7) & 7) << 4))),
                      vals[i] * ALPHA);
        }
        __syncthreads();
#pragma unroll
        for (int i = 0; i < 4; i++) {
            int b = 64 * t + 16 * i;
            sp[i] = *(const float4*)(ab + (b ^ (((b >> 7) & 7) << 4)));
        }
    }

    float w[16];
    {
        int pv[8] = {p0.x, p0.y, p0.z, p0.w, p1.x, p1.y, p1.z, p1.w};
#pragma unroll
        for (int q = 0; q < 8; q++) {
            w[2 * q]     = (float)((pv[q] & 0xF) - 8) * s;
            w[2 * q + 1] = (float)(((pv[q] >> 4) & 0xF) - 8) * s;
        }
    }
    const float* spf = (const float*)sp;
    float mx = 0.f;
#pragma unroll
    for (int k = 0; k < 16; k++) {
        w[k] += spf[k];
        mx = fmaxf(mx, fabsf(w[k]));
    }
#pragma unroll
    for (int o = 32; o > 0; o >>= 1) mx = fmaxf(mx, __shfl_xor(mx, o));
    if ((t & 63) == 0) red[t >> 6] = mx;
    __syncthreads();
    mx = fmaxf(fmaxf(red[0], red[1]), fmaxf(red[2], red[3]));
    mx = fmaxf(mx, 1e-20f);
    if (t == 0) sw[r] = mx / 127.f;
    const float inv = 127.f / mx;

    union { signed char c[16]; int4 v; } u;
#pragma unroll
    for (int k = 0; k < 16; k++) u.c[k] = q8(w[k], inv);
    ((int4*)(W8 + (size_t)r * 4096))[t] = u.v;
}

// ---------------------------------------------------------------------------
// Kernel 3: int8 NT GEMM — ROUND-3 PROVEN VERSION (105.5-105.9 us), verbatim.
//   BM=128, BN=256, BK=128 bytes, 512 thr = 8 waves (2M x 4N), 64x64/wave.
//   Triple-buffered LDS, prefetch distance 2, steady-state vmcnt(6);
//   register-pipelined phases, 1 barrier/iter; fragment reads of freshly
//   staged buffers only after vmcnt+barrier (vmcnt is per-wave!).
//   NOTE (r6/r7 lesson): A must stay LDS-staged — direct-from-global A
//   misses L2 (4 MB/XCD, thrashed by ~32 concurrent B streams) and exposes
//   L3/HBM latency every iteration (FETCH 131->360 MB, MfmaUtil 38->14).
// ---------------------------------------------------------------------------
__global__ __launch_bounds__(512) void gemm_kernel(
    const signed char* __restrict__ Xq,   // [M,K] i8
    const signed char* __restrict__ Wq,   // [N,K] i8
    const float* __restrict__ sx,         // [M]
    const float* __restrict__ sw,         // [N]
    float* __restrict__ C,                // [M,N] fp32
    int M, int N, int K) {
    __shared__ __align__(16) signed char smem[3 * 49152];

    const int tid  = threadIdx.x;
    const int wid  = tid >> 6;
    const int lane = tid & 63;
    const int wr = wid >> 2;        // 0..1 (M)
    const int wc = wid & 3;         // 0..3 (N)

    // bijective XCD-chunked block swizzle (nwg = 688, %8 == 0)
    const int nwg = gridDim.x;
    const int bid = blockIdx.x;
    const int qc = nwg >> 3, rr = nwg & 7;
    const int xcd = bid & 7, loc = bid >> 3;
    const int swz = (xcd < rr ? xcd * (qc + 1) : rr * (qc + 1) + (xcd - rr) * qc) + loc;
    const int tm = M >> 7;
    const int mt = swz % tm;
    const int nt = swz / tm;
    const int m0 = mt << 7;
    const int n0 = nt << 8;

    // staging: gload_lds dest linear, global SOURCE pre-swizzled (rule 21)
    const int sr = tid >> 3;                         // row (load0); load1 = +64
    const int sc = ((tid & 7) ^ (sr & 7)) << 4;      // swizzled src byte col
    const int lw0 = wid << 10;
    const int lw1 = 8192 + (wid << 10);

    const signed char* Ax  = Xq + (size_t)m0 * K;
    const signed char* Bw0 = Wq + (size_t)n0 * K;
    const signed char* Bw1 = Wq + (size_t)(n0 + 128) * K;

#define STAGE(gbase, ldsbase) do {                                         \
        async16((gbase) + (size_t)sr * K + sc, (ldsbase) + lw0);           \
        async16((gbase) + (size_t)(sr + 64) * K + sc, (ldsbase) + lw1);    \
    } while (0)

    // fragment read constants
    const int fm = lane & 15;
    const int slot0 = ((lane >> 4) ^ (lane & 7)) << 4;   // k-substep 0
    const int slot1 = slot0 ^ 64;                        // k-substep 1
    const int arow_base = wr * 64;
    const int brow_base = wc * 64;

#define LDA(buf, mi, sl) \
    (*(const i32x4*)((buf) + (size_t)(arow_base + (mi) * 16 + fm) * 128 + (sl)))
#define LDB(buf, nj, sl) \
    (*(const i32x4*)((buf) + 16384 + (size_t)(brow_base + (nj) * 16 + fm) * 128 + (sl)))

#define MFMA8(m0i, m1i, aX, aY, B0, B1, B2, B3) do {                        \
        __builtin_amdgcn_s_setprio(1);                                      \
        acc[m0i][0] = __builtin_amdgcn_mfma_i32_16x16x64_i8(aX, B0, acc[m0i][0], 0, 0, 0); \
        acc[m1i][0] = __builtin_amdgcn_mfma_i32_16x16x64_i8(aY, B0, acc[m1i][0], 0, 0, 0); \
        acc[m0i][1] = __builtin_amdgcn_mfma_i32_16x16x64_i8(aX, B1, acc[m0i][1], 0, 0, 0); \
        acc[m1i][1] = __builtin_amdgcn_mfma_i32_16x16x64_i8(aY, B1, acc[m1i][1], 0, 0, 0); \
        acc[m0i][2] = __builtin_amdgcn_mfma_i32_16x16x64_i8(aX, B2, acc[m0i][2], 0, 0, 0); \
        acc[m1i][2] = __builtin_amdgcn_mfma_i32_16x16x64_i8(aY, B2, acc[m1i][2], 0, 0, 0); \
        acc[m0i][3] = __builtin_amdgcn_mfma_i32_16x16x64_i8(aX, B3, acc[m0i][3], 0, 0, 0); \
        acc[m1i][3] = __builtin_amdgcn_mfma_i32_16x16x64_i8(aY, B3, acc[m1i][3], 0, 0, 0); \
        __builtin_amdgcn_s_setprio(0);                                      \
    } while (0)

    i32x4 acc[4][4];
#pragma unroll
    for (int i = 0; i < 4; i++)
#pragma unroll
        for (int j = 0; j < 4; j++) acc[i][j] = (i32x4){0, 0, 0, 0};

    const int NT = K >> 7;   // 128-byte K-tiles (32)

    // prologue: stage T0 -> buf0, T1 -> buf1; wait T0 (oldest 6 of 12)
    STAGE(Ax,        smem);
    STAGE(Bw0,       smem + 16384);
    STAGE(Bw1,       smem + 32768);
    STAGE(Ax  + 128, smem + 49152);
    STAGE(Bw0 + 128, smem + 49152 + 16384);
    STAGE(Bw1 + 128, smem + 49152 + 32768);
    asm volatile("s_waitcnt vmcnt(6)" ::: "memory");
    __builtin_amdgcn_s_barrier();
    __builtin_amdgcn_sched_barrier(0);

    int cur = 0;
    for (int it = 0; it < NT; ++it) {
        signed char* Ab = smem + cur * 49152;
        int pb = cur + 2; if (pb >= 3) pb -= 3;
        signed char* PA = smem + pb * 49152;
        const bool pref = (it + 2 < NT);
        const int kc = (it + 2) << 7;

        // p0 (top-of-iter, after barrier): read ks0 frags of THIS tile,
        // plus next phase's A rows; stage A of tile it+2; MFMA rows 0-1 ks0
        i32x4 a0  = LDA(Ab, 0, slot0), a1  = LDA(Ab, 1, slot0);
        i32x4 bA0 = LDB(Ab, 0, slot0), bA1 = LDB(Ab, 1, slot0),
              bA2 = LDB(Ab, 2, slot0), bA3 = LDB(Ab, 3, slot0);
        i32x4 na0 = LDA(Ab, 2, slot0), na1 = LDA(Ab, 3, slot0);
        if (pref) STAGE(Ax + kc, PA);
        MFMA8(0, 1, a0, a1, bA0, bA1, bA2, bA3);

        // p1: issue B ks1 + A(0,1) ks1; MFMA rows 2-3 x ks0
        i32x4 bB0 = LDB(Ab, 0, slot1), bB1 = LDB(Ab, 1, slot1),
              bB2 = LDB(Ab, 2, slot1), bB3 = LDB(Ab, 3, slot1);
        i32x4 ma0 = LDA(Ab, 0, slot1), ma1 = LDA(Ab, 1, slot1);
        if (pref) STAGE(Bw0 + kc, PA + 16384);
        MFMA8(2, 3, na0, na1, bA0, bA1, bA2, bA3);

        // p2: issue A(2,3) ks1; MFMA rows 0-1 x ks1
        i32x4 pa2 = LDA(Ab, 2, slot1), pa3 = LDA(Ab, 3, slot1);
        if (pref) STAGE(Bw1 + kc, PA + 32768);
        MFMA8(0, 1, ma0, ma1, bB0, bB1, bB2, bB3);

        // p3: counted vmcnt (tile it+1 fully landed), MFMA rows 2-3 x ks1,
        // then the single end-of-iter barrier
        if (it + 2 < NT)       { asm volatile("s_waitcnt vmcnt(6)" ::: "memory"); }
        else if (it + 2 == NT) { asm volatile("s_waitcnt vmcnt(0)" ::: "memory"); }
        MFMA8(2, 3, pa2, pa3, bB0, bB1, bB2, bB3);

        __builtin_amdgcn_s_barrier();
        __builtin_amdgcn_sched_barrier(0);
        cur += 1; if (cur == 3) cur = 0;
    }
#undef STAGE
#undef LDA
#undef LDB
#undef MFMA8

    // epilogue: C/D layout col = lane&15, row = (lane>>4)*4 + reg
    const int cr = (lane >> 4) << 2;
    const int cc = lane & 15;
#pragma unroll
    for (int mi = 0; mi < 4; ++mi) {
        const int row0 = m0 + wr * 64 + mi * 16 + cr;
        float sxv[4];
#pragma unroll
        for (int r = 0; r < 4; ++r) sxv[r] = sx[row0 + r];
#pragma unroll
        for (int nj = 0; nj < 4; ++nj) {
            const int col = n0 + wc * 64 + nj * 16 + cc;
            const float swc = sw[col];
            float* cp = C + (size_t)row0 * N + col;
#pragma unroll
            for (int r = 0; r < 4; ++r)
                cp[(size_t)r * N] = (float)acc[mi][nj][r] * sxv[r] * swc;
        }
    }
}

extern "C" void kernel_launch(void* const* d_in, const int* in_sizes, int n_in,
                              void* d_out, int out_size, void* d_ws, size_t ws_size,
                              hipStream_t stream) {
    const float* x      = (const float*)d_in[0];
    const float* scales = (const float*)d_in[1];
    const float* vals   = (const float*)d_in[2];
    const int* packed   = (const int*)d_in[3];
    const int* rows     = (const int*)d_in[4];
    const int* cols     = (const int*)d_in[5];
    float* out          = (float*)d_out;

    const int OUT  = in_sizes[1];            // 11008
    const int HALF = in_sizes[3] / OUT;      // 2048
    const int IN   = HALF * 2;               // 4096
    const int M    = in_sizes[0] / IN;       // 2048 tokens
    const int NNZ  = in_sizes[2];            // 2250000

    // workspace: i8 W [OUT,IN] | i8 X [M,IN] | sx[M] | sw[OUT] | rstart | rend
    signed char* W8 = (signed char*)d_ws;
    signed char* X8 = W8 + (size_t)OUT * IN;
    float* sx   = (float*)(X8 + (size_t)M * IN);
    float* sw   = sx + M;
    int* rstart = (int*)(sw + OUT);
    int* rend   = rstart + OUT;

    const int boundsBlocks = (NNZ + 255) / 256;
    prep_kernel<<<M + boundsBlocks, 256, 0, stream>>>(x, rows, rstart, rend,
                                                      X8, sx, M, NNZ);
    build_w8_kernel<<<OUT, 256, 0, stream>>>(packed, scales, vals, cols,
                                             rstart, rend, W8, sw);
    const int nwg = (M / 128) * (OUT / 256);   // 16 * 43 = 688, %8 == 0
    gemm_kernel<<<nwg, 512, 0, stream>>>(X8, W8, sx, sw, out, M, OUT, IN);
}